// Round 2
// baseline (9340.083 us; speedup 1.0000x reference)
//
#include <hip/hip_runtime.h>
#include <hip/hip_bf16.h>
#include <stdint.h>

#define TK 64
#define FDIM 16384
#define DDIM 2048
#define NCAP 128

// ---------------------------------------------------------------------------
// Kernel 1: encode GEMM  z = relu(x @ W_enc + b_enc)   (f32 vector ALU)
// 128x128 tile, BK=16, 256 threads, 8x8 microtile per thread.
// ---------------------------------------------------------------------------
#define BM 128
#define BN 128
#define BKT 16

__global__ __launch_bounds__(256) void enc_gemm_f32(
    const float* __restrict__ A,    // [Mchunk, DDIM]
    const float* __restrict__ Bw,   // [DDIM, FDIM]
    const float* __restrict__ bias, // [FDIM]
    float* __restrict__ Cz)         // [Mchunk, FDIM]
{
  constexpr int Kd = DDIM, N = FDIM;
  __shared__ float As[BKT][BM];
  __shared__ float Bs[BKT][BN];
  const int tid  = threadIdx.x;
  const int col0 = blockIdx.x * BN;
  const int row0 = blockIdx.y * BM;
  const int tn = tid & 15, tm = tid >> 4;

  float acc[8][8];
#pragma unroll
  for (int i = 0; i < 8; ++i)
#pragma unroll
    for (int j = 0; j < 8; ++j) acc[i][j] = 0.f;

  for (int k0 = 0; k0 < Kd; k0 += BKT) {
#pragma unroll
    for (int s = 0; s < 2; ++s) {
      int lin = tid + s * 256;
      int ar = lin >> 2, aq = lin & 3;
      float4 av = *(const float4*)(A + (size_t)(row0 + ar) * Kd + k0 + aq * 4);
      As[aq * 4 + 0][ar] = av.x;
      As[aq * 4 + 1][ar] = av.y;
      As[aq * 4 + 2][ar] = av.z;
      As[aq * 4 + 3][ar] = av.w;
      int br = lin >> 5, bq = lin & 31;
      float4 bv = *(const float4*)(Bw + (size_t)(k0 + br) * N + col0 + bq * 4);
      *(float4*)&Bs[br][bq * 4] = bv;
    }
    __syncthreads();
#pragma unroll
    for (int k = 0; k < BKT; ++k) {
      float a[8], b[8];
      *(float4*)&a[0] = *(const float4*)&As[k][tm * 8];
      *(float4*)&a[4] = *(const float4*)&As[k][tm * 8 + 4];
      *(float4*)&b[0] = *(const float4*)&Bs[k][tn * 8];
      *(float4*)&b[4] = *(const float4*)&Bs[k][tn * 8 + 4];
#pragma unroll
      for (int i = 0; i < 8; ++i)
#pragma unroll
        for (int j = 0; j < 8; ++j) acc[i][j] = fmaf(a[i], b[j], acc[i][j]);
    }
    __syncthreads();
  }

  float bb[8];
#pragma unroll
  for (int j = 0; j < 8; ++j) bb[j] = bias[col0 + tn * 8 + j];
#pragma unroll
  for (int i = 0; i < 8; ++i) {
    float* cr = Cz + (size_t)(row0 + tm * 8 + i) * N + col0 + tn * 8;
    float4 v0, v1;
    v0.x = fmaxf(acc[i][0] + bb[0], 0.f);
    v0.y = fmaxf(acc[i][1] + bb[1], 0.f);
    v0.z = fmaxf(acc[i][2] + bb[2], 0.f);
    v0.w = fmaxf(acc[i][3] + bb[3], 0.f);
    v1.x = fmaxf(acc[i][4] + bb[4], 0.f);
    v1.y = fmaxf(acc[i][5] + bb[5], 0.f);
    v1.z = fmaxf(acc[i][6] + bb[6], 0.f);
    v1.w = fmaxf(acc[i][7] + bb[7], 0.f);
    *(float4*)cr       = v0;
    *(float4*)(cr + 4) = v1;
  }
}

// ---------------------------------------------------------------------------
// Kernel 2: per-row exact top-64 via radix select + f64 boundary rescue.
// Selection near the rank-64 threshold is re-scored with f64 dot products so
// our top-64 SET equals the true (and hence numpy-f32) selection.
// Output: 64 (idx,val) pairs per row, sorted by idx.
// ---------------------------------------------------------------------------
__global__ __launch_bounds__(256) void topk_kernel(
    const float* __restrict__ z,     // [Rchunk, FDIM]
    const float* __restrict__ x,     // [Rchunk, DDIM] (chunk-offset)
    const float* __restrict__ Wenc,  // [DDIM, FDIM]
    const float* __restrict__ benc,  // [FDIM]
    int*   __restrict__ outIdx,      // [Rchunk, TK]
    float* __restrict__ outVal)      // [Rchunk, TK]
{
  const int row = blockIdx.x;
  const int tid = threadIdx.x;
  const float* zr = z + (size_t)row * FDIM;

  __shared__ float zs[FDIM];          // 64 KB
  __shared__ unsigned int hist[256];
  __shared__ int sSel, sCumAbove;
  __shared__ int nsel, eqseen;
  __shared__ int wq[4];
  __shared__ int   sIdx[TK];
  __shared__ float sVal[TK];
  __shared__ int cIdxS[NCAP];
  __shared__ float cValS[NCAP];
  __shared__ double dVals[NCAP];
  __shared__ int keepFlag[NCAP];
  __shared__ int tIdx[TK];
  __shared__ float tVal[TK];
  __shared__ double dred[256];
  __shared__ int ncand, winSel;

  for (int i4 = tid; i4 < FDIM / 4; i4 += 256)
    ((float4*)zs)[i4] = ((const float4*)zr)[i4];
  if (tid == 0) { nsel = 0; eqseen = 0; ncand = 0; winSel = 0; }
  __syncthreads();

  // ---- radix select: exact key of the 64th largest (z>=0 so bits monotone)
  unsigned pref = 0;
  int r = TK;
  for (int p = 0; p < 4; ++p) {
    hist[tid & 255] = 0;
    __syncthreads();
    const int sh = 24 - 8 * p;
    const unsigned hiMask = (p == 0) ? 0u : (0xFFFFFFFFu << (sh + 8));
    for (int i = tid; i < FDIM; i += 256) {
      unsigned key = __float_as_uint(zs[i]);
      if ((key & hiMask) == pref) atomicAdd(&hist[(key >> sh) & 0xFF], 1u);
    }
    __syncthreads();
    if (tid == 0) {
      int cum = 0, b = 255;
      for (; b >= 0; --b) {
        cum += (int)hist[b];
        if (cum >= r) break;
      }
      sSel = b;
      sCumAbove = cum - (int)hist[b];
    }
    __syncthreads();
    pref |= ((unsigned)sSel) << sh;
    r -= sCumAbove;
    __syncthreads();
  }
  const unsigned T = pref;  // key of rank-64 value; keep first-r equals

  // ---- deterministic compaction: key > T, plus first-r (by index) == T
  for (int base = 0; base < FDIM; base += 256) {
    const int i = base + tid;
    const unsigned key = __float_as_uint(zs[i]);
    const bool gt = key > T;
    const bool eq = (key == T);
    const unsigned long long beq = __ballot(eq);
    const int lane = tid & 63, wv = tid >> 6;
    if (lane == 0) wq[wv] = __popcll(beq);
    __syncthreads();
    int qb = eqseen;
    for (int w = 0; w < wv; ++w) qb += wq[w];
    const int myq = __popcll(beq & ((1ull << lane) - 1ull));
    const bool sel = gt || (eq && (qb + myq) < r);
    if (sel) {
      int p = atomicAdd(&nsel, 1);
      if (p < TK) { sIdx[p] = i; sVal[p] = zs[i]; }
    }
    __syncthreads();
    if (tid == 0) eqseen += wq[0] + wq[1] + wq[2] + wq[3];
    __syncthreads();
  }
  __syncthreads();

  // ---- f64 boundary rescue --------------------------------------------
  const float v64 = __uint_as_float(T);
  const float M = 2.5e-3f;   // >> f32 GEMM noise (~2e-6), << typical gap
  for (int i = tid; i < FDIM; i += 256) {
    float zv = zs[i];
    if (fabsf(zv - v64) <= M) {
      int p = atomicAdd(&ncand, 1);
      if (p < NCAP) { cIdxS[p] = i; cValS[p] = zv; }
    }
  }
  if (tid < TK && fabsf(sVal[tid] - v64) <= M) atomicAdd(&winSel, 1);
  __syncthreads();
  int nc = ncand < NCAP ? ncand : NCAP;
  if (nc > winSel) {
    // rescore every window candidate with an f64 dot product
    for (int c = 0; c < nc; ++c) {
      const int f = cIdxS[c];
      double part = 0.0;
      for (int k = tid; k < DDIM; k += 256)
        part += (double)x[(size_t)row * DDIM + k] *
                (double)Wenc[(size_t)k * FDIM + f];
      dred[tid] = part;
      __syncthreads();
      for (int s = 128; s > 0; s >>= 1) {
        if (tid < s) dred[tid] += dred[tid + s];
        __syncthreads();
      }
      if (tid == 0) dVals[c] = dred[0] + (double)benc[f];
      __syncthreads();
    }
    if (tid == 0) {
      for (int c = 0; c < nc; ++c) keepFlag[c] = 0;
      int take = winSel < nc ? winSel : nc;
      for (int t = 0; t < take; ++t) {
        int best = -1;
        for (int c = 0; c < nc; ++c) {
          if (keepFlag[c]) continue;
          if (best < 0 || dVals[c] > dVals[best] ||
              (dVals[c] == dVals[best] && cIdxS[c] < cIdxS[best])) best = c;
        }
        keepFlag[best] = 1;
      }
      // rebuild the 64-set: safe selected (outside window) + chosen window
      int n = 0;
      for (int t = 0; t < TK; ++t)
        if (fabsf(sVal[t] - v64) > M) {
          tIdx[n] = sIdx[t]; tVal[n] = sVal[t]; ++n;
        }
      for (int c = 0; c < nc && n < TK; ++c)
        if (keepFlag[c]) { tIdx[n] = cIdxS[c]; tVal[n] = cValS[c]; ++n; }
    }
    __syncthreads();
    if (tid < TK) { sIdx[tid] = tIdx[tid]; sVal[tid] = tVal[tid]; }
    __syncthreads();
  }

  // ---- sort the 64 pairs by index (odd-even transposition) ----
  for (int ph = 0; ph < TK; ++ph) {
    if (tid < TK - 1 && (tid & 1) == (ph & 1)) {
      if (sIdx[tid] > sIdx[tid + 1]) {
        int ti = sIdx[tid]; sIdx[tid] = sIdx[tid + 1]; sIdx[tid + 1] = ti;
        float tv = sVal[tid]; sVal[tid] = sVal[tid + 1]; sVal[tid + 1] = tv;
      }
    }
    __syncthreads();
  }

  if (tid < TK) {
    outIdx[(size_t)row * TK + tid] = sIdx[tid];
    outVal[(size_t)row * TK + tid] = sVal[tid];
  }
}

// ---------------------------------------------------------------------------
// Kernel 3: decode  recon = sparse_z @ W_dec + b_dec.  One block per row.
// ---------------------------------------------------------------------------
__global__ __launch_bounds__(256) void decode_kernel(
    const int*   __restrict__ idxL,  // [Rchunk, TK]
    const float* __restrict__ valL,  // [Rchunk, TK]
    const float* __restrict__ Wd,    // [FDIM, DDIM]
    const float* __restrict__ bd,    // [DDIM]
    float* __restrict__ out)         // [Rchunk, DDIM]
{
  const int row = blockIdx.x;
  const int tid = threadIdx.x;
  __shared__ int   si[TK];
  __shared__ float sv[TK];
  if (tid < TK) {
    si[tid] = idxL[(size_t)row * TK + tid];
    sv[tid] = valL[(size_t)row * TK + tid];
  }
  __syncthreads();

  float4 a0 = ((const float4*)bd)[tid];
  float4 a1 = ((const float4*)bd)[256 + tid];

#pragma unroll 4
  for (int t = 0; t < TK; ++t) {
    const int f = si[t];
    const float v = sv[t];
    const float4* wr = (const float4*)(Wd + (size_t)f * DDIM);
    float4 w0 = wr[tid];
    float4 w1 = wr[256 + tid];
    a0.x = fmaf(v, w0.x, a0.x); a0.y = fmaf(v, w0.y, a0.y);
    a0.z = fmaf(v, w0.z, a0.z); a0.w = fmaf(v, w0.w, a0.w);
    a1.x = fmaf(v, w1.x, a1.x); a1.y = fmaf(v, w1.y, a1.y);
    a1.z = fmaf(v, w1.z, a1.z); a1.w = fmaf(v, w1.w, a1.w);
  }
  float4* orow = (float4*)(out + (size_t)row * DDIM);
  orow[tid]       = a0;
  orow[256 + tid] = a1;
}

// ---------------------------------------------------------------------------
extern "C" void kernel_launch(void* const* d_in, const int* in_sizes, int n_in,
                              void* d_out, int out_size, void* d_ws, size_t ws_size,
                              hipStream_t stream) {
  const float* x    = (const float*)d_in[0];  // [B, D]
  const float* Wenc = (const float*)d_in[1];  // [D, F]
  const float* benc = (const float*)d_in[2];  // [F]
  const float* Wdec = (const float*)d_in[3];  // [F, D]
  const float* bdec = (const float*)d_in[4];  // [D]
  float* out = (float*)d_out;

  const int D = in_sizes[4];          // 2048
  const int B = in_sizes[0] / D;      // 8192

  // workspace layout: [idx list B*TK int][val list B*TK float][z chunk]
  char* ws = (char*)d_ws;
  int*   idxL = (int*)ws;
  float* valL = (float*)(ws + (size_t)B * TK * 4);
  size_t zOff = (size_t)B * TK * 8;
  zOff = (zOff + 255) & ~(size_t)255;
  float* z = (float*)(ws + zOff);

  size_t zBytes = (ws_size > zOff) ? (ws_size - zOff) : 0;
  long   zRows  = (long)(zBytes / ((size_t)FDIM * 4));
  int R = (int)((zRows / 128) * 128);
  if (R > B) R = B;
  if (R < 128) R = 128;  // assume ws is at least ~12.5 MB

  for (int r0 = 0; r0 < B; r0 += R) {
    int rows = (B - r0 < R) ? (B - r0) : R;
    dim3 g(FDIM / BN, rows / BM);
    enc_gemm_f32<<<g, 256, 0, stream>>>(x + (size_t)r0 * D, Wenc, benc, z);
    topk_kernel<<<rows, 256, 0, stream>>>(z, x + (size_t)r0 * D, Wenc, benc,
                                          idxL, valL);
    decode_kernel<<<rows, 256, 0, stream>>>(idxL, valL, Wdec, bdec,
                                            out + (size_t)r0 * D);
  }
}

// Round 3
// 4386.522 us; speedup vs baseline: 2.1293x; 2.1293x over previous
//
#include <hip/hip_runtime.h>
#include <hip/hip_bf16.h>
#include <stdint.h>

#define TK 64
#define FDIM 16384
#define DDIM 2048
#define NCAP 128

typedef __attribute__((ext_vector_type(8))) short bf16x8;
typedef __attribute__((ext_vector_type(4))) float f32x4;

#define GLL(g, p)                                                        \
  __builtin_amdgcn_global_load_lds(                                      \
      (const __attribute__((address_space(1))) uint32_t*)(g),            \
      (__attribute__((address_space(3))) uint32_t*)(p), 16, 0, 0)

__device__ __forceinline__ unsigned short f2bf(float a) {
  union { float f; uint32_t u; } p; p.f = a;
  uint32_t u = p.u;
  return (unsigned short)((u + 0x7FFFu + ((u >> 16) & 1u)) >> 16);
}
__device__ __forceinline__ float bf2f(unsigned short h) {
  union { uint32_t u; float f; } p; p.u = ((uint32_t)h) << 16; return p.f;
}

// ---------------------------------------------------------------------------
// conv_x: f32 [B][D] -> bf16 hi/lo [B][D]
// ---------------------------------------------------------------------------
__global__ __launch_bounds__(256) void conv_x(
    const float* __restrict__ x, unsigned short* __restrict__ xh,
    unsigned short* __restrict__ xl, int n4)
{
  int i = blockIdx.x * 256 + threadIdx.x;
  const int stride = gridDim.x * 256;
  for (; i < n4; i += stride) {
    float4 v = ((const float4*)x)[i];
    ushort4 h, lo;
    h.x = f2bf(v.x); lo.x = f2bf(v.x - bf2f(h.x));
    h.y = f2bf(v.y); lo.y = f2bf(v.y - bf2f(h.y));
    h.z = f2bf(v.z); lo.z = f2bf(v.z - bf2f(h.z));
    h.w = f2bf(v.w); lo.w = f2bf(v.w - bf2f(h.w));
    ((ushort4*)xh)[i] = h;
    ((ushort4*)xl)[i] = lo;
  }
}

// ---------------------------------------------------------------------------
// conv_w: W_enc f32 [D][F] -> transposed bf16 hi/lo [F][D]
// ---------------------------------------------------------------------------
__global__ __launch_bounds__(256) void conv_w(
    const float* __restrict__ W, unsigned short* __restrict__ wh,
    unsigned short* __restrict__ wl)
{
  __shared__ float t[32][33];
  const int f0 = blockIdx.x * 32, d0 = blockIdx.y * 32;
  const int tr = threadIdx.x >> 3;
  const int tc = (threadIdx.x & 7) * 4;
  float4 v = *(const float4*)(W + (size_t)(d0 + tr) * FDIM + f0 + tc);
  t[tr][tc + 0] = v.x; t[tr][tc + 1] = v.y;
  t[tr][tc + 2] = v.z; t[tr][tc + 3] = v.w;
  __syncthreads();
  float a0 = t[tc + 0][tr], a1 = t[tc + 1][tr];
  float a2 = t[tc + 2][tr], a3 = t[tc + 3][tr];
  ushort4 h, lo;
  h.x = f2bf(a0); lo.x = f2bf(a0 - bf2f(h.x));
  h.y = f2bf(a1); lo.y = f2bf(a1 - bf2f(h.y));
  h.z = f2bf(a2); lo.z = f2bf(a2 - bf2f(h.z));
  h.w = f2bf(a3); lo.w = f2bf(a3 - bf2f(h.w));
  *(ushort4*)(wh + (size_t)(f0 + tr) * DDIM + d0 + tc) = h;
  *(ushort4*)(wl + (size_t)(f0 + tr) * DDIM + d0 + tc) = lo;
}

// ---------------------------------------------------------------------------
// Kernel 1: encode GEMM via split-bf16 MFMA (3 products; xl*wl dropped).
// 128x128 tile, BK=32, 4 waves, global_load_lds staging with XOR chunk
// swizzle on BOTH the global source and the LDS read (G21).
// ---------------------------------------------------------------------------
__global__ __launch_bounds__(256) void enc_gemm_bf16x3(
    const unsigned short* __restrict__ xh,  // [Rchunk][DDIM] bf16
    const unsigned short* __restrict__ xl,
    const unsigned short* __restrict__ wh,  // [FDIM][DDIM] bf16 (W^T)
    const unsigned short* __restrict__ wl,
    const float* __restrict__ bias,         // [FDIM]
    float* __restrict__ Cz)                 // [Rchunk][FDIM]
{
  __shared__ __align__(16) char smem[32768];  // Ah,Al,Bh,Bl tiles 8KB each
  const int tid = threadIdx.x;
  const int l = tid & 63;
  const int w = tid >> 6;
  const int wm = w >> 1, wn = w & 1;
  const int row0 = blockIdx.y * 128;
  const int col0 = blockIdx.x * 128;

  f32x4 acc[4][4] = {};

  // staging constants: thread covers LDS 16B slot (r=i*64+(tid>>2), c=tid&3);
  // that slot holds global chunk g = c ^ ((r>>1)&3)  (indep. of i: 32i%4==0)
  const int sr = tid >> 2;
  const int sg = (tid & 3) ^ ((sr >> 1) & 3);
  const char* gxh = (const char*)xh + (size_t)row0 * 4096 + sg * 16;
  const char* gxl = (const char*)xl + (size_t)row0 * 4096 + sg * 16;
  const char* gwh = (const char*)wh + (size_t)col0 * 4096 + sg * 16;
  const char* gwl = (const char*)wl + (size_t)col0 * 4096 + sg * 16;

  // read-side lane base: row (l&15), chunk c = (l>>4) ^ ((l>>1)&3)
  const int lb = (l & 15) * 64 + (((l >> 4) ^ ((l >> 1) & 3)) << 4);
  const int aoff = wm * 4096 + lb;
  const int boff = wn * 4096 + lb;

  for (int k0 = 0; k0 < DDIM; k0 += 32) {
    __syncthreads();
    const size_t kb = (size_t)k0 * 2;
#pragma unroll
    for (int i = 0; i < 2; ++i) {
      const size_t ro = (size_t)(i * 64 + sr) * 4096 + kb;
      char* lp = smem + i * 4096 + w * 1024;
      GLL(gxh + ro, lp);
      GLL(gxl + ro, lp + 8192);
      GLL(gwh + ro, lp + 16384);
      GLL(gwl + ro, lp + 24576);
    }
    __syncthreads();

    bf16x8 ah[4], al[4], bh[4], bl[4];
#pragma unroll
    for (int f = 0; f < 4; ++f) {
      ah[f] = *(const bf16x8*)(smem + aoff + f * 1024);
      al[f] = *(const bf16x8*)(smem + 8192 + aoff + f * 1024);
      bh[f] = *(const bf16x8*)(smem + 16384 + boff + f * 1024);
      bl[f] = *(const bf16x8*)(smem + 24576 + boff + f * 1024);
    }
#pragma unroll
    for (int fm = 0; fm < 4; ++fm)
#pragma unroll
      for (int fn = 0; fn < 4; ++fn) {
        acc[fm][fn] = __builtin_amdgcn_mfma_f32_16x16x32_bf16(
            ah[fm], bh[fn], acc[fm][fn], 0, 0, 0);
        acc[fm][fn] = __builtin_amdgcn_mfma_f32_16x16x32_bf16(
            ah[fm], bl[fn], acc[fm][fn], 0, 0, 0);
        acc[fm][fn] = __builtin_amdgcn_mfma_f32_16x16x32_bf16(
            al[fm], bh[fn], acc[fm][fn], 0, 0, 0);
      }
  }

  // epilogue: bias + relu, scalar stores (16-lane coalesced)
#pragma unroll
  for (int fn = 0; fn < 4; ++fn) {
    const int col = col0 + wn * 64 + fn * 16 + (l & 15);
    const float bb = bias[col];
#pragma unroll
    for (int fm = 0; fm < 4; ++fm) {
#pragma unroll
      for (int q = 0; q < 4; ++q) {
        const int rz = row0 + wm * 64 + fm * 16 + (l >> 4) * 4 + q;
        Cz[(size_t)rz * FDIM + col] = fmaxf(acc[fm][fn][q] + bb, 0.f);
      }
    }
  }
}

// ---------------------------------------------------------------------------
// Kernel 2: per-row exact top-64 via radix select + f64 boundary rescue.
// ---------------------------------------------------------------------------
__global__ __launch_bounds__(256) void topk_kernel(
    const float* __restrict__ z,     // [Rchunk, FDIM]
    const float* __restrict__ x,     // [Rchunk, DDIM] (chunk-offset)
    const float* __restrict__ Wenc,  // [DDIM, FDIM]
    const float* __restrict__ benc,  // [FDIM]
    int*   __restrict__ outIdx,      // [Rchunk, TK]
    float* __restrict__ outVal)      // [Rchunk, TK]
{
  const int row = blockIdx.x;
  const int tid = threadIdx.x;
  const float* zr = z + (size_t)row * FDIM;

  __shared__ float zs[FDIM];
  __shared__ unsigned int hist[256];
  __shared__ int sSel, sCumAbove;
  __shared__ int nsel, eqseen;
  __shared__ int wq[4];
  __shared__ int   sIdx[TK];
  __shared__ float sVal[TK];
  __shared__ int cIdxS[NCAP];
  __shared__ float cValS[NCAP];
  __shared__ double dVals[NCAP];
  __shared__ int keepFlag[NCAP];
  __shared__ int tIdx[TK];
  __shared__ float tVal[TK];
  __shared__ double dred[256];
  __shared__ int ncand, winSel;

  for (int i4 = tid; i4 < FDIM / 4; i4 += 256)
    ((float4*)zs)[i4] = ((const float4*)zr)[i4];
  if (tid == 0) { nsel = 0; eqseen = 0; ncand = 0; winSel = 0; }
  __syncthreads();

  unsigned pref = 0;
  int r = TK;
  for (int p = 0; p < 4; ++p) {
    hist[tid & 255] = 0;
    __syncthreads();
    const int sh = 24 - 8 * p;
    const unsigned hiMask = (p == 0) ? 0u : (0xFFFFFFFFu << (sh + 8));
    for (int i = tid; i < FDIM; i += 256) {
      unsigned key = __float_as_uint(zs[i]);
      if ((key & hiMask) == pref) atomicAdd(&hist[(key >> sh) & 0xFF], 1u);
    }
    __syncthreads();
    if (tid == 0) {
      int cum = 0, b = 255;
      for (; b >= 0; --b) {
        cum += (int)hist[b];
        if (cum >= r) break;
      }
      sSel = b;
      sCumAbove = cum - (int)hist[b];
    }
    __syncthreads();
    pref |= ((unsigned)sSel) << sh;
    r -= sCumAbove;
    __syncthreads();
  }
  const unsigned T = pref;

  for (int base = 0; base < FDIM; base += 256) {
    const int i = base + tid;
    const unsigned key = __float_as_uint(zs[i]);
    const bool gt = key > T;
    const bool eq = (key == T);
    const unsigned long long beq = __ballot(eq);
    const int lane = tid & 63, wv = tid >> 6;
    if (lane == 0) wq[wv] = __popcll(beq);
    __syncthreads();
    int qb = eqseen;
    for (int w = 0; w < wv; ++w) qb += wq[w];
    const int myq = __popcll(beq & ((1ull << lane) - 1ull));
    const bool sel = gt || (eq && (qb + myq) < r);
    if (sel) {
      int p = atomicAdd(&nsel, 1);
      if (p < TK) { sIdx[p] = i; sVal[p] = zs[i]; }
    }
    __syncthreads();
    if (tid == 0) eqseen += wq[0] + wq[1] + wq[2] + wq[3];
    __syncthreads();
  }
  __syncthreads();

  // f64 boundary rescue
  const float v64 = __uint_as_float(T);
  const float M = 2.5e-3f;
  for (int i = tid; i < FDIM; i += 256) {
    float zv = zs[i];
    if (fabsf(zv - v64) <= M) {
      int p = atomicAdd(&ncand, 1);
      if (p < NCAP) { cIdxS[p] = i; cValS[p] = zv; }
    }
  }
  if (tid < TK && fabsf(sVal[tid] - v64) <= M) atomicAdd(&winSel, 1);
  __syncthreads();
  int nc = ncand < NCAP ? ncand : NCAP;
  if (nc > winSel) {
    for (int c = 0; c < nc; ++c) {
      const int f = cIdxS[c];
      double part = 0.0;
      for (int k = tid; k < DDIM; k += 256)
        part += (double)x[(size_t)row * DDIM + k] *
                (double)Wenc[(size_t)k * FDIM + f];
      dred[tid] = part;
      __syncthreads();
      for (int s = 128; s > 0; s >>= 1) {
        if (tid < s) dred[tid] += dred[tid + s];
        __syncthreads();
      }
      if (tid == 0) dVals[c] = dred[0] + (double)benc[f];
      __syncthreads();
    }
    if (tid == 0) {
      for (int c = 0; c < nc; ++c) keepFlag[c] = 0;
      int take = winSel < nc ? winSel : nc;
      for (int t = 0; t < take; ++t) {
        int best = -1;
        for (int c = 0; c < nc; ++c) {
          if (keepFlag[c]) continue;
          if (best < 0 || dVals[c] > dVals[best] ||
              (dVals[c] == dVals[best] && cIdxS[c] < cIdxS[best])) best = c;
        }
        keepFlag[best] = 1;
      }
      int n = 0;
      for (int t = 0; t < TK; ++t)
        if (fabsf(sVal[t] - v64) > M) {
          tIdx[n] = sIdx[t]; tVal[n] = sVal[t]; ++n;
        }
      for (int c = 0; c < nc && n < TK; ++c)
        if (keepFlag[c]) { tIdx[n] = cIdxS[c]; tVal[n] = cValS[c]; ++n; }
    }
    __syncthreads();
    if (tid < TK) { sIdx[tid] = tIdx[tid]; sVal[tid] = tVal[tid]; }
    __syncthreads();
  }

  for (int ph = 0; ph < TK; ++ph) {
    if (tid < TK - 1 && (tid & 1) == (ph & 1)) {
      if (sIdx[tid] > sIdx[tid + 1]) {
        int ti = sIdx[tid]; sIdx[tid] = sIdx[tid + 1]; sIdx[tid + 1] = ti;
        float tv = sVal[tid]; sVal[tid] = sVal[tid + 1]; sVal[tid + 1] = tv;
      }
    }
    __syncthreads();
  }

  if (tid < TK) {
    outIdx[(size_t)row * TK + tid] = sIdx[tid];
    outVal[(size_t)row * TK + tid] = sVal[tid];
  }
}

// ---------------------------------------------------------------------------
// Kernel 3: decode  recon = sparse_z @ W_dec + b_dec.  One block per row.
// ---------------------------------------------------------------------------
__global__ __launch_bounds__(256) void decode_kernel(
    const int*   __restrict__ idxL,
    const float* __restrict__ valL,
    const float* __restrict__ Wd,
    const float* __restrict__ bd,
    float* __restrict__ out)
{
  const int row = blockIdx.x;
  const int tid = threadIdx.x;
  __shared__ int   si[TK];
  __shared__ float sv[TK];
  if (tid < TK) {
    si[tid] = idxL[(size_t)row * TK + tid];
    sv[tid] = valL[(size_t)row * TK + tid];
  }
  __syncthreads();

  float4 a0 = ((const float4*)bd)[tid];
  float4 a1 = ((const float4*)bd)[256 + tid];

#pragma unroll 4
  for (int t = 0; t < TK; ++t) {
    const int f = si[t];
    const float v = sv[t];
    const float4* wr = (const float4*)(Wd + (size_t)f * DDIM);
    float4 w0 = wr[tid];
    float4 w1 = wr[256 + tid];
    a0.x = fmaf(v, w0.x, a0.x); a0.y = fmaf(v, w0.y, a0.y);
    a0.z = fmaf(v, w0.z, a0.z); a0.w = fmaf(v, w0.w, a0.w);
    a1.x = fmaf(v, w1.x, a1.x); a1.y = fmaf(v, w1.y, a1.y);
    a1.z = fmaf(v, w1.z, a1.z); a1.w = fmaf(v, w1.w, a1.w);
  }
  float4* orow = (float4*)(out + (size_t)row * DDIM);
  orow[tid]       = a0;
  orow[256 + tid] = a1;
}

// ---------------------------------------------------------------------------
extern "C" void kernel_launch(void* const* d_in, const int* in_sizes, int n_in,
                              void* d_out, int out_size, void* d_ws, size_t ws_size,
                              hipStream_t stream) {
  const float* x    = (const float*)d_in[0];
  const float* Wenc = (const float*)d_in[1];
  const float* benc = (const float*)d_in[2];
  const float* Wdec = (const float*)d_in[3];
  const float* bdec = (const float*)d_in[4];
  float* out = (float*)d_out;

  const int D = in_sizes[4];          // 2048
  const int B = in_sizes[0] / D;      // 8192

  // ws layout: idx | val | Wt_h | Wt_l | x_h | x_l | z(chunked)
  char* ws = (char*)d_ws;
  size_t off = 0;
  int*   idxL = (int*)ws;            off += (size_t)B * TK * 4;
  float* valL = (float*)(ws + off);  off += (size_t)B * TK * 4;
  off = (off + 255) & ~(size_t)255;
  unsigned short* wth = (unsigned short*)(ws + off); off += (size_t)FDIM * DDIM * 2;
  unsigned short* wtl = (unsigned short*)(ws + off); off += (size_t)FDIM * DDIM * 2;
  unsigned short* xh  = (unsigned short*)(ws + off); off += (size_t)B * DDIM * 2;
  unsigned short* xl  = (unsigned short*)(ws + off); off += (size_t)B * DDIM * 2;
  off = (off + 255) & ~(size_t)255;
  float* z = (float*)(ws + off);

  size_t zBytes = (ws_size > off) ? (ws_size - off) : 0;
  long   zRows  = (long)(zBytes / ((size_t)FDIM * 4));
  int R = (int)((zRows / 128) * 128);
  if (R > B) R = B;
  if (R < 128) R = 128;

  conv_x<<<2048, 256, 0, stream>>>(x, xh, xl, B * D / 4);
  conv_w<<<dim3(FDIM / 32, DDIM / 32), 256, 0, stream>>>(Wenc, wth, wtl);

  for (int r0 = 0; r0 < B; r0 += R) {
    int rows = (B - r0 < R) ? (B - r0) : R;
    dim3 g(FDIM / 128, rows / 128);
    enc_gemm_bf16x3<<<g, 256, 0, stream>>>(xh + (size_t)r0 * D,
                                           xl + (size_t)r0 * D,
                                           wth, wtl, benc, z);
    topk_kernel<<<rows, 256, 0, stream>>>(z, x + (size_t)r0 * D, Wenc, benc,
                                          idxL, valL);
    decode_kernel<<<rows, 256, 0, stream>>>(idxL, valL, Wdec, bdec,
                                            out + (size_t)r0 * D);
  }
}

// Round 4
// 2850.204 us; speedup vs baseline: 3.2770x; 1.5390x over previous
//
#include <hip/hip_runtime.h>
#include <hip/hip_bf16.h>
#include <stdint.h>

#define TK 64
#define FDIM 16384
#define DDIM 2048
#define NCAP 128
#define CCAP 320

typedef __attribute__((ext_vector_type(8))) short bf16x8;
typedef __attribute__((ext_vector_type(4))) float f32x4;

#define GLL(g, p)                                                        \
  __builtin_amdgcn_global_load_lds(                                      \
      (const __attribute__((address_space(1))) uint32_t*)(g),            \
      (__attribute__((address_space(3))) uint32_t*)(p), 16, 0, 0)

__device__ __forceinline__ unsigned short f2bf(float a) {
  union { float f; uint32_t u; } p; p.f = a;
  uint32_t u = p.u;
  return (unsigned short)((u + 0x7FFFu + ((u >> 16) & 1u)) >> 16);
}
__device__ __forceinline__ float bf2f(unsigned short h) {
  union { uint32_t u; float f; } p; p.u = ((uint32_t)h) << 16; return p.f;
}

// ---------------------------------------------------------------------------
// conv_x: f32 [B][D] -> bf16 hi/lo [B][D]
// ---------------------------------------------------------------------------
__global__ __launch_bounds__(256) void conv_x(
    const float* __restrict__ x, unsigned short* __restrict__ xh,
    unsigned short* __restrict__ xl, int n4)
{
  int i = blockIdx.x * 256 + threadIdx.x;
  const int stride = gridDim.x * 256;
  for (; i < n4; i += stride) {
    float4 v = ((const float4*)x)[i];
    ushort4 h, lo;
    h.x = f2bf(v.x); lo.x = f2bf(v.x - bf2f(h.x));
    h.y = f2bf(v.y); lo.y = f2bf(v.y - bf2f(h.y));
    h.z = f2bf(v.z); lo.z = f2bf(v.z - bf2f(h.z));
    h.w = f2bf(v.w); lo.w = f2bf(v.w - bf2f(h.w));
    ((ushort4*)xh)[i] = h;
    ((ushort4*)xl)[i] = lo;
  }
}

// ---------------------------------------------------------------------------
// conv_w: W_enc f32 [D][F] -> transposed bf16 hi/lo [F][D]
// ---------------------------------------------------------------------------
__global__ __launch_bounds__(256) void conv_w(
    const float* __restrict__ W, unsigned short* __restrict__ wh,
    unsigned short* __restrict__ wl)
{
  __shared__ float t[32][33];
  const int f0 = blockIdx.x * 32, d0 = blockIdx.y * 32;
  const int tr = threadIdx.x >> 3;
  const int tc = (threadIdx.x & 7) * 4;
  float4 v = *(const float4*)(W + (size_t)(d0 + tr) * FDIM + f0 + tc);
  t[tr][tc + 0] = v.x; t[tr][tc + 1] = v.y;
  t[tr][tc + 2] = v.z; t[tr][tc + 3] = v.w;
  __syncthreads();
  float a0 = t[tc + 0][tr], a1 = t[tc + 1][tr];
  float a2 = t[tc + 2][tr], a3 = t[tc + 3][tr];
  ushort4 h, lo;
  h.x = f2bf(a0); lo.x = f2bf(a0 - bf2f(h.x));
  h.y = f2bf(a1); lo.y = f2bf(a1 - bf2f(h.y));
  h.z = f2bf(a2); lo.z = f2bf(a2 - bf2f(h.z));
  h.w = f2bf(a3); lo.w = f2bf(a3 - bf2f(h.w));
  *(ushort4*)(wh + (size_t)(f0 + tr) * DDIM + d0 + tc) = h;
  *(ushort4*)(wl + (size_t)(f0 + tr) * DDIM + d0 + tc) = lo;
}

// ---------------------------------------------------------------------------
// Kernel 1: encode GEMM via split-bf16 MFMA (3 products; xl*wl dropped).
// 128x128 tile, BK=32, 4 waves, global_load_lds + XOR source/read swizzle.
// XCD-aware bijective block swizzle (grid 8192 % 8 == 0).
// ---------------------------------------------------------------------------
__global__ __launch_bounds__(256) void enc_gemm_bf16x3(
    const unsigned short* __restrict__ xh,  // [Rchunk][DDIM] bf16
    const unsigned short* __restrict__ xl,
    const unsigned short* __restrict__ wh,  // [FDIM][DDIM] bf16 (W^T)
    const unsigned short* __restrict__ wl,
    const float* __restrict__ bias,         // [FDIM]
    float* __restrict__ Cz)                 // [Rchunk][FDIM]
{
  __shared__ __align__(16) char smem[32768];  // Ah,Al,Bh,Bl tiles 8KB each
  const int tid = threadIdx.x;
  const int l = tid & 63;
  const int w = tid >> 6;
  const int wm = w >> 1, wn = w & 1;

  // XCD-aware bijective swizzle of the linear block id
  const int nbx = gridDim.x;
  const int lin = blockIdx.y * nbx + blockIdx.x;
  const int nwg = nbx * gridDim.y;
  const int cpx = nwg >> 3;                 // nwg % 8 == 0 guaranteed
  const int swz = (lin & 7) * cpx + (lin >> 3);
  const int row0 = (swz / nbx) * 128;
  const int col0 = (swz % nbx) * 128;

  f32x4 acc[4][4] = {};

  // staging: thread covers LDS 16B slot (r=i*64+(tid>>2), c=tid&3);
  // that slot holds global chunk g = c ^ ((r>>1)&3)
  const int sr = tid >> 2;
  const int sg = (tid & 3) ^ ((sr >> 1) & 3);
  const char* gxh = (const char*)xh + (size_t)row0 * 4096 + sg * 16;
  const char* gxl = (const char*)xl + (size_t)row0 * 4096 + sg * 16;
  const char* gwh = (const char*)wh + (size_t)col0 * 4096 + sg * 16;
  const char* gwl = (const char*)wl + (size_t)col0 * 4096 + sg * 16;

  // read-side lane base: row (l&15), chunk c = (l>>4) ^ ((l>>1)&3)
  const int lb = (l & 15) * 64 + (((l >> 4) ^ ((l >> 1) & 3)) << 4);
  const int aoff = wm * 4096 + lb;
  const int boff = wn * 4096 + lb;

  for (int k0 = 0; k0 < DDIM; k0 += 32) {
    __syncthreads();
    const size_t kb = (size_t)k0 * 2;
#pragma unroll
    for (int i = 0; i < 2; ++i) {
      const size_t ro = (size_t)(i * 64 + sr) * 4096 + kb;
      char* lp = smem + i * 4096 + w * 1024;
      GLL(gxh + ro, lp);
      GLL(gxl + ro, lp + 8192);
      GLL(gwh + ro, lp + 16384);
      GLL(gwl + ro, lp + 24576);
    }
    __syncthreads();

    bf16x8 ah[4], al[4], bh[4], bl[4];
#pragma unroll
    for (int f = 0; f < 4; ++f) {
      ah[f] = *(const bf16x8*)(smem + aoff + f * 1024);
      al[f] = *(const bf16x8*)(smem + 8192 + aoff + f * 1024);
      bh[f] = *(const bf16x8*)(smem + 16384 + boff + f * 1024);
      bl[f] = *(const bf16x8*)(smem + 24576 + boff + f * 1024);
    }
#pragma unroll
    for (int fm = 0; fm < 4; ++fm)
#pragma unroll
      for (int fn = 0; fn < 4; ++fn) {
        acc[fm][fn] = __builtin_amdgcn_mfma_f32_16x16x32_bf16(
            ah[fm], bh[fn], acc[fm][fn], 0, 0, 0);
        acc[fm][fn] = __builtin_amdgcn_mfma_f32_16x16x32_bf16(
            ah[fm], bl[fn], acc[fm][fn], 0, 0, 0);
        acc[fm][fn] = __builtin_amdgcn_mfma_f32_16x16x32_bf16(
            al[fm], bh[fn], acc[fm][fn], 0, 0, 0);
      }
  }

#pragma unroll
  for (int fn = 0; fn < 4; ++fn) {
    const int col = col0 + wn * 64 + fn * 16 + (l & 15);
    const float bb = bias[col];
#pragma unroll
    for (int fm = 0; fm < 4; ++fm) {
#pragma unroll
      for (int q = 0; q < 4; ++q) {
        const int rz = row0 + wm * 64 + fm * 16 + (l >> 4) * 4 + q;
        Cz[(size_t)rz * FDIM + col] = fmaxf(acc[fm][fn][q] + bb, 0.f);
      }
    }
  }
}

// ---------------------------------------------------------------------------
// Kernel 2: per-row exact top-64 via threshold candidate pruning.
// One coalesced scan collects elems > T (~200 of 16384); exact rank among
// candidates (val desc, idx asc = jax tie-break); f64 boundary rescue
// identical in semantics to the verified R2/R3 version.
// ---------------------------------------------------------------------------
__global__ __launch_bounds__(256) void topk_kernel(
    const float* __restrict__ z,     // [Rchunk, FDIM]
    const float* __restrict__ x,     // [Rchunk, DDIM] (chunk-offset)
    const float* __restrict__ Wenc,  // [DDIM, FDIM]
    const float* __restrict__ benc,  // [FDIM]
    int*   __restrict__ outIdx,      // [Rchunk, TK]
    float* __restrict__ outVal)      // [Rchunk, TK]
{
  const int row = blockIdx.x;
  const int tid = threadIdx.x;
  const float* zr = z + (size_t)row * FDIM;

  __shared__ int    cIdx[CCAP];
  __shared__ float  cVal[CCAP];
  __shared__ short  sRank[CCAP];
  __shared__ unsigned char selF[CCAP];
  __shared__ int    cnt;
  __shared__ float  sV64;
  __shared__ int    wList[NCAP];
  __shared__ int    nW, winSel;
  __shared__ double dVals[NCAP];
  __shared__ int    keepFlag[NCAP];
  __shared__ double dred[256];

  // ---- candidate scan with bounded threshold retry ----
  float T = 2.25f;
  int nc = 0;
  for (int attempt = 0; attempt < 16; ++attempt) {
    if (tid == 0) cnt = 0;
    __syncthreads();
    for (int i4 = tid; i4 < FDIM / 4; i4 += 256) {
      float4 v = ((const float4*)zr)[i4];
      const int i0 = i4 * 4;
      if (v.x > T) { int p = atomicAdd(&cnt, 1); if (p < CCAP) { cIdx[p] = i0 + 0; cVal[p] = v.x; } }
      if (v.y > T) { int p = atomicAdd(&cnt, 1); if (p < CCAP) { cIdx[p] = i0 + 1; cVal[p] = v.y; } }
      if (v.z > T) { int p = atomicAdd(&cnt, 1); if (p < CCAP) { cIdx[p] = i0 + 2; cVal[p] = v.z; } }
      if (v.w > T) { int p = atomicAdd(&cnt, 1); if (p < CCAP) { cIdx[p] = i0 + 3; cVal[p] = v.w; } }
    }
    __syncthreads();
    nc = cnt;
    __syncthreads();          // protect cnt from next-iter reset
    if (nc >= TK && nc <= CCAP) break;
    T += (nc > CCAP) ? 0.25f : -0.5f;
  }
  if (nc > CCAP) nc = CCAP;

  // ---- exact rank among candidates (strict total order) ----
  for (int c = tid; c < nc; c += 256) {
    const float vi = cVal[c];
    const int   ii = cIdx[c];
    int rk = 0;
    for (int j = 0; j < nc; ++j) {
      const float vj = cVal[j];
      rk += (vj > vi) || (vj == vi && cIdx[j] < ii);
    }
    sRank[c] = (short)rk;
    selF[c] = (rk < TK) ? 1 : 0;
    if (rk == TK - 1) sV64 = vi;
  }
  __syncthreads();
  const float v64 = sV64;
  const float M = 2.5e-3f;

  // ---- window collection (from candidate list) ----
  if (tid == 0) { nW = 0; winSel = 0; }
  __syncthreads();
  for (int c = tid; c < nc; c += 256) {
    if (fabsf(cVal[c] - v64) <= M) {
      int p = atomicAdd(&nW, 1);
      if (p < NCAP) wList[p] = c;
      if (sRank[c] < TK) atomicAdd(&winSel, 1);
    }
  }
  __syncthreads();
  // guard: if window bottom could fall below scan threshold, rescan row
  if (v64 - M <= T) {
    for (int i4 = tid; i4 < FDIM / 4; i4 += 256) {
      float4 v = ((const float4*)zr)[i4];
      const int i0 = i4 * 4;
      float vv[4] = {v.x, v.y, v.z, v.w};
#pragma unroll
      for (int q = 0; q < 4; ++q) {
        if (vv[q] <= T && fabsf(vv[q] - v64) <= M) {
          int p = atomicAdd(&cnt, 1);       // append as candidate
          if (p < CCAP) {
            cIdx[p] = i0 + q; cVal[p] = vv[q];
            sRank[p] = (short)CCAP; selF[p] = 0;
            int pw = atomicAdd(&nW, 1);
            if (pw < NCAP) wList[pw] = p;
          }
        }
      }
    }
    __syncthreads();
    nc = (cnt < CCAP) ? cnt : CCAP;
  }
  const int nw = (nW < NCAP) ? nW : NCAP;

  // ---- f64 boundary rescue (semantics identical to verified version) ----
  if (nw > winSel) {
    for (int c = 0; c < nw; ++c) {
      const int f = cIdx[wList[c]];
      double part = 0.0;
      for (int k = tid; k < DDIM; k += 256)
        part += (double)x[(size_t)row * DDIM + k] *
                (double)Wenc[(size_t)k * FDIM + f];
      dred[tid] = part;
      __syncthreads();
      for (int s = 128; s > 0; s >>= 1) {
        if (tid < s) dred[tid] += dred[tid + s];
        __syncthreads();
      }
      if (tid == 0) dVals[c] = dred[0] + (double)benc[f];
      __syncthreads();
    }
    if (tid == 0) {
      for (int c = 0; c < nw; ++c) keepFlag[c] = 0;
      int take = winSel < nw ? winSel : nw;
      for (int t = 0; t < take; ++t) {
        int best = -1;
        for (int c = 0; c < nw; ++c) {
          if (keepFlag[c]) continue;
          if (best < 0 || dVals[c] > dVals[best] ||
              (dVals[c] == dVals[best] && cIdx[wList[c]] < cIdx[wList[best]]))
            best = c;
        }
        keepFlag[best] = 1;
      }
      for (int c = 0; c < nw; ++c) selF[wList[c]] = (unsigned char)keepFlag[c];
    }
    __syncthreads();
  }

  // ---- emit 64 (idx,val) pairs ordered by feature idx ----
  for (int c = tid; c < nc; c += 256) {
    if (selF[c]) {
      const int myIdx = cIdx[c];
      int pos = 0;
      for (int j = 0; j < nc; ++j)
        pos += (selF[j] && cIdx[j] < myIdx);
      outIdx[(size_t)row * TK + pos] = myIdx;
      outVal[(size_t)row * TK + pos] = cVal[c];
    }
  }
}

// ---------------------------------------------------------------------------
// Kernel 3: decode  recon = sparse_z @ W_dec + b_dec.  One block per row.
// ---------------------------------------------------------------------------
__global__ __launch_bounds__(256) void decode_kernel(
    const int*   __restrict__ idxL,
    const float* __restrict__ valL,
    const float* __restrict__ Wd,
    const float* __restrict__ bd,
    float* __restrict__ out)
{
  const int row = blockIdx.x;
  const int tid = threadIdx.x;
  __shared__ int   si[TK];
  __shared__ float sv[TK];
  if (tid < TK) {
    si[tid] = idxL[(size_t)row * TK + tid];
    sv[tid] = valL[(size_t)row * TK + tid];
  }
  __syncthreads();

  float4 a0 = ((const float4*)bd)[tid];
  float4 a1 = ((const float4*)bd)[256 + tid];

#pragma unroll 4
  for (int t = 0; t < TK; ++t) {
    const int f = si[t];
    const float v = sv[t];
    const float4* wr = (const float4*)(Wd + (size_t)f * DDIM);
    float4 w0 = wr[tid];
    float4 w1 = wr[256 + tid];
    a0.x = fmaf(v, w0.x, a0.x); a0.y = fmaf(v, w0.y, a0.y);
    a0.z = fmaf(v, w0.z, a0.z); a0.w = fmaf(v, w0.w, a0.w);
    a1.x = fmaf(v, w1.x, a1.x); a1.y = fmaf(v, w1.y, a1.y);
    a1.z = fmaf(v, w1.z, a1.z); a1.w = fmaf(v, w1.w, a1.w);
  }
  float4* orow = (float4*)(out + (size_t)row * DDIM);
  orow[tid]       = a0;
  orow[256 + tid] = a1;
}

// ---------------------------------------------------------------------------
extern "C" void kernel_launch(void* const* d_in, const int* in_sizes, int n_in,
                              void* d_out, int out_size, void* d_ws, size_t ws_size,
                              hipStream_t stream) {
  const float* x    = (const float*)d_in[0];
  const float* Wenc = (const float*)d_in[1];
  const float* benc = (const float*)d_in[2];
  const float* Wdec = (const float*)d_in[3];
  const float* bdec = (const float*)d_in[4];
  float* out = (float*)d_out;

  const int D = in_sizes[4];          // 2048
  const int B = in_sizes[0] / D;      // 8192

  // ws layout: idx | val | Wt_h | Wt_l | x_h | x_l | z(chunked)
  char* ws = (char*)d_ws;
  size_t off = 0;
  int*   idxL = (int*)ws;            off += (size_t)B * TK * 4;
  float* valL = (float*)(ws + off);  off += (size_t)B * TK * 4;
  off = (off + 255) & ~(size_t)255;
  unsigned short* wth = (unsigned short*)(ws + off); off += (size_t)FDIM * DDIM * 2;
  unsigned short* wtl = (unsigned short*)(ws + off); off += (size_t)FDIM * DDIM * 2;
  unsigned short* xh  = (unsigned short*)(ws + off); off += (size_t)B * DDIM * 2;
  unsigned short* xl  = (unsigned short*)(ws + off); off += (size_t)B * DDIM * 2;
  off = (off + 255) & ~(size_t)255;
  float* z = (float*)(ws + off);

  size_t zBytes = (ws_size > off) ? (ws_size - off) : 0;
  long   zRows  = (long)(zBytes / ((size_t)FDIM * 4));
  int R = (int)((zRows / 128) * 128);
  if (R > B) R = B;
  if (R < 128) R = 128;

  conv_x<<<2048, 256, 0, stream>>>(x, xh, xl, B * D / 4);
  conv_w<<<dim3(FDIM / 32, DDIM / 32), 256, 0, stream>>>(Wenc, wth, wtl);

  for (int r0 = 0; r0 < B; r0 += R) {
    int rows = (B - r0 < R) ? (B - r0) : R;
    dim3 g(FDIM / 128, rows / 128);
    enc_gemm_bf16x3<<<g, 256, 0, stream>>>(xh + (size_t)r0 * D,
                                           xl + (size_t)r0 * D,
                                           wth, wtl, benc, z);
    topk_kernel<<<rows, 256, 0, stream>>>(z, x + (size_t)r0 * D, Wenc, benc,
                                          idxL, valL);
    decode_kernel<<<rows, 256, 0, stream>>>(idxL, valL, Wdec, bdec,
                                            out + (size_t)r0 * D);
  }
}